// Round 12
// baseline (640.347 us; speedup 1.0000x reference)
//
#include <hip/hip_runtime.h>
#include <hip/hip_bf16.h>
#include <math.h>

#define SEQ 2048
#define NH 8
#define DK 64
#define DM 512
#define RSCALE 0.125f
#define PPAD (SEQ + 128)
#define POFF 64
#define KSTR 72   // K LDS row stride (bf16 el): 144B = 16B-aligned, 2-way banks
#define PSTR 36   // E1 LDS row stride (f32)

typedef unsigned short ushortT;
typedef short s16x8 __attribute__((ext_vector_type(8)));
typedef float f32x4 __attribute__((ext_vector_type(4)));

#define MFMA16 __builtin_amdgcn_mfma_f32_16x16x32_bf16

static __device__ __forceinline__ ushortT f2bf(float x) {
  __hip_bfloat16 h = __float2bfloat16(x);
  ushortT u;
  __builtin_memcpy(&u, &h, 2);
  return u;
}

static __device__ __forceinline__ f32x4 exp4(f32x4 g) {
  f32x4 r;
  r[0] = __expf(g[0]); r[1] = __expf(g[1]);
  r[2] = __expf(g[2]); r[3] = __expf(g[3]);
  return r;
}

static __device__ __forceinline__ s16x8 pack8(const float* p) {
  ushortT u[8];
#pragma unroll
  for (int i = 0; i < 8; ++i) u[i] = f2bf(p[i]);
  s16x8 out;
  __builtin_memcpy(&out, u, 16);
  return out;
}

// pi^-1: j-local column -> A-frag k-slot  (pi(q*8+jj) = jj<4 ? 4q+jj : 16+4q+jj-4)
static __device__ __forceinline__ int pinv(int j) {
  return (j < 16) ? ((j >> 2) * 8 + (j & 3)) : (((j >> 2) - 4) * 8 + 4 + (j & 3));
}

// ---- cast X (4M el) and PE (1M el) to bf16, vectorized x4 ----
__global__ __launch_bounds__(256)
void cast_in(const float* __restrict__ X, const float* __restrict__ PE,
             ushortT* __restrict__ Xb, ushortT* __restrict__ PEb) {
  const size_t i4 = (size_t)blockIdx.x * 256 + threadIdx.x;
  const size_t NX = (size_t)4 * SEQ * DM / 4;
  const float4 v = (i4 < NX) ? *(const float4*)(X + i4 * 4)
                             : *(const float4*)(PE + (i4 - NX) * 4);
  ushortT o[4] = {f2bf(v.x), f2bf(v.y), f2bf(v.z), f2bf(v.w)};
  ushortT* dst = (i4 < NX) ? (Xb + i4 * 4) : (PEb + (i4 - NX) * 4);
  *(ulonglong1*)dst = *(ulonglong1*)o;
}

// ---- transpose 5 weights 512x512 fp32 -> bf16 [n][k], contiguous ----
__global__ __launch_bounds__(256)
void transpose_w(const float* __restrict__ w0, const float* __restrict__ w1,
                 const float* __restrict__ w2, const float* __restrict__ w3,
                 const float* __restrict__ w4, ushortT* __restrict__ out) {
  __shared__ float ts[32][33];
  const int z = blockIdx.z;
  const float* w = (z == 0) ? w0 : (z == 1) ? w1 : (z == 2) ? w2 : (z == 3) ? w3 : w4;
  ushortT* o = out + (size_t)z * DM * DM;
  const int k0 = blockIdx.x * 32, n0 = blockIdx.y * 32;
  const int tx = threadIdx.x, ty = threadIdx.y;
#pragma unroll
  for (int i = 0; i < 4; ++i)
    ts[ty + i * 8][tx] = w[(size_t)(k0 + ty + i * 8) * DM + n0 + tx];
  __syncthreads();
#pragma unroll
  for (int i = 0; i < 4; ++i)
    o[(size_t)(n0 + ty + i * 8) * DM + k0 + tx] = f2bf(ts[tx][ty + i * 8]);
}

// ---- bf16 MFMA GEMM ----
// mode 0: fused QKV, Bt = [Wq^T;Wk^T;Wv^T] (N=1536). z=gn>>9 selects output:
//   z0: qu/qv = bf16((acc+u/v)*RSCALE) [bh][s][d]; z1: kb [bh][s][d];
//   z2: vt [bh][d][s'] with within-32 pi-permuted column s'
// mode 3 (P): qu <- bf16 [h][POFF+s][d];  mode 4: of fp32 [m][n]
__global__ __launch_bounds__(256)
void gemm_mfma(const ushortT* __restrict__ A, const ushortT* __restrict__ Bt,
               const float* __restrict__ ubv, const float* __restrict__ vbv,
               ushortT* __restrict__ qu, ushortT* __restrict__ qv,
               ushortT* __restrict__ kb, ushortT* __restrict__ vt,
               float* __restrict__ of, int mode) {
  const int w = threadIdx.x >> 6, lane = threadIdx.x & 63;
  const int c = lane & 15, q = lane >> 4;
  const int m0 = blockIdx.x * 64;
  const int n0 = blockIdx.y * 128 + w * 32;

  const ushortT* Ab = A + (size_t)m0 * DM + q * 8;
  const ushortT* Bb = Bt + (size_t)n0 * DM + q * 8;

  f32x4 acc[4][2];
#pragma unroll
  for (int mt = 0; mt < 4; ++mt)
#pragma unroll
    for (int nt = 0; nt < 2; ++nt) acc[mt][nt] = (f32x4){0.f, 0.f, 0.f, 0.f};

  s16x8 a[4], bfr[2], an[4], bn[2];
#pragma unroll
  for (int mt = 0; mt < 4; ++mt) a[mt] = *(const s16x8*)(Ab + (size_t)(mt * 16 + c) * DM);
#pragma unroll
  for (int nt = 0; nt < 2; ++nt) bfr[nt] = *(const s16x8*)(Bb + (size_t)(nt * 16 + c) * DM);

  for (int k0 = 0; k0 < DM; k0 += 32) {
    if (k0 + 32 < DM) {
#pragma unroll
      for (int mt = 0; mt < 4; ++mt)
        an[mt] = *(const s16x8*)(Ab + (size_t)(mt * 16 + c) * DM + k0 + 32);
#pragma unroll
      for (int nt = 0; nt < 2; ++nt)
        bn[nt] = *(const s16x8*)(Bb + (size_t)(nt * 16 + c) * DM + k0 + 32);
    }
#pragma unroll
    for (int mt = 0; mt < 4; ++mt)
#pragma unroll
      for (int nt = 0; nt < 2; ++nt)
        acc[mt][nt] = MFMA16(a[mt], bfr[nt], acc[mt][nt], 0, 0, 0);
#pragma unroll
    for (int mt = 0; mt < 4; ++mt) a[mt] = an[mt];
#pragma unroll
    for (int nt = 0; nt < 2; ++nt) bfr[nt] = bn[nt];
  }

#pragma unroll
  for (int mt = 0; mt < 4; ++mt)
#pragma unroll
    for (int nt = 0; nt < 2; ++nt)
#pragma unroll
      for (int r = 0; r < 4; ++r) {
        const int gm = m0 + mt * 16 + q * 4 + r;
        const int gn = n0 + nt * 16 + c;
        const float v = acc[mt][nt][r];
        const int bb = gm >> 11, s = gm & (SEQ - 1);
        if (mode == 0) {
          const int z = gn >> 9, gn5 = gn & 511;
          const int h = gn5 >> 6, d = gn5 & 63;
          if (z == 0) {
            const size_t base = (((size_t)bb * NH + h) * SEQ + s) * DK + d;
            qu[base] = f2bf((v + ubv[gn5]) * RSCALE);
            qv[base] = f2bf((v + vbv[gn5]) * RSCALE);
          } else if (z == 1) {
            kb[(((size_t)bb * NH + h) * SEQ + s) * DK + d] = f2bf(v);
          } else {
            const int s_il = (s & ~31) | pinv(s & 31);
            vt[(((size_t)bb * NH + h) * DK + d) * SEQ + s_il] = f2bf(v);
          }
        } else if (mode == 3) {
          const int h = gn >> 6, d = gn & 63;
          qu[((size_t)h * PPAD + POFF + gm) * DK + d] = f2bf(v);
        } else {
          of[(size_t)gm * DM + gn] = v;
        }
      }
}

// ---- band GEMM helper: G = Qrow-block x P[tile*16 .. +15]  (P from L2) ----
static __device__ __forceinline__ f32x4 band_gemm(const ushortT* pb, int tile,
                                                  int c, int q, s16x8 a0, s16x8 a1) {
  const ushortT* pc = pb + (ptrdiff_t)(tile * 16 + c) * DK + q * 8;
  f32x4 G = {0.f, 0.f, 0.f, 0.f};
  G = MFMA16(a0, *(const s16x8*)pc, G, 0, 0, 0);
  G = MFMA16(a1, *(const s16x8*)(pc + 32), G, 0, 0, 0);
  return G;
}

// ---- MFMA flash relative attention: dbuf LDS K, global V, slim LDS ----
__global__ __launch_bounds__(256, 5)
void attn_mfma(const ushortT* __restrict__ Qu, const ushortT* __restrict__ Qv,
               const ushortT* __restrict__ Kb, const ushortT* __restrict__ Vt,
               const ushortT* __restrict__ Pp, ushortT* __restrict__ ctxb) {
  const int n = blockIdx.x;
  const int xcd = n & 7, idx = n >> 3;      // XCD x serves h=x (L2 locality)
  const int b = idx >> 5, iblk = idx & 31;
  const int h = xcd, bh = b * 8 + h;
  const int tid = threadIdx.x;
  const int w = tid >> 6, lane = tid & 63;
  const int c = lane & 15, q = lane >> 4;
  const int i0 = iblk * 64;
  const int iw = i0 + w * 16;

  __shared__ ushortT Ks[2][64][KSTR];
  __shared__ float E1[4][16][PSTR];   // exp(G) band, pi-slotted cols (per wave)
  __shared__ float Lb[4][16];

  const ushortT* Qub = Qu + ((size_t)bh * SEQ + iw) * DK;
  const ushortT* Qvb = Qv + ((size_t)bh * SEQ + iw) * DK;
  const ushortT* Kbh = Kb + (size_t)bh * SEQ * DK;
  const ushortT* Vbh = Vt + (size_t)bh * DK * SEQ;
  const ushortT* Ph  = Pp + ((size_t)h * PPAD + POFF) * DK;

  const s16x8 qu0 = *(const s16x8*)(Qub + (size_t)c * DK + q * 8);
  const s16x8 qu1 = *(const s16x8*)(Qub + (size_t)c * DK + 32 + q * 8);
  s16x8 qv0 = *(const s16x8*)(Qvb + (size_t)c * DK + q * 8);
  s16x8 qv1 = *(const s16x8*)(Qvb + (size_t)c * DK + 32 + q * 8);

  // per-slot j-local offsets: pi(q*8+jj)
  int joff[8];
#pragma unroll
  for (int jj = 0; jj < 8; ++jj)
    joff[jj] = (jj < 4) ? (4 * q + jj) : (16 + 4 * q + (jj - 4));

  f32x4 O[4];
#pragma unroll
  for (int r = 0; r < 4; ++r) O[r] = (f32x4){0.f, 0.f, 0.f, 0.f};
  float lrow = 0.f;
  f32x4 e[3];
  bool hv1 = false, hv2 = false;
  const int jt = iw & ~31;
  const int m_w = q * 4;

  // ---- prologue: stage chunk 0 into Ks[0] ----
  {
    uint4 k0v = *(const uint4*)(Kbh + tid * 8);
    uint4 k1v = *(const uint4*)(Kbh + 2048 + tid * 8);
    *(uint4*)&Ks[0][tid >> 3][(tid & 7) * 8] = k0v;
    *(uint4*)&Ks[0][32 + (tid >> 3)][(tid & 7) * 8] = k1v;
  }
  __syncthreads();

#define WRITE_BAND(ev)                                                        \
  _Pragma("unroll")                                                           \
  for (int t = 0; t < 3; ++t)                                                 \
    _Pragma("unroll")                                                         \
    for (int r = 0; r < 4; ++r) {                                             \
      const int kcol = t * 16 + c + (m_w + r) - 15;                           \
      if (kcol >= 0 && kcol < 32) E1[w][m_w + r][pinv(kcol)] = (ev)[t][r];    \
    }

#define PV_FROM(pr, j0g)                                                      \
  {                                                                           \
    lrow += pr[0] + pr[1] + pr[2] + pr[3] + pr[4] + pr[5] + pr[6] + pr[7];    \
    const s16x8 pa = pack8(pr);                                               \
    _Pragma("unroll")                                                         \
    for (int dt = 0; dt < 4; ++dt) {                                          \
      const s16x8 vb = *(const s16x8*)(Vbh + (size_t)(dt * 16 + c) * SEQ + (j0g) + q * 8); \
      O[dt] = MFMA16(pa, vb, O[dt], 0, 0, 0);                                 \
    }                                                                         \
  }

  for (int ch = 0; ch < 32; ++ch) {
    const int cur = ch & 1;
    const bool more = (ch + 1) < 32;
    uint4 k0v, k1v;
    if (more) {  // prefetch next K chunk (latency overlaps compute)
      const ushortT* gk = Kbh + (size_t)(ch + 1) * 64 * DK;
      k0v = *(const uint4*)(gk + tid * 8);
      k1v = *(const uint4*)(gk + 2048 + tid * 8);
    }
#pragma unroll
    for (int t = 0; t < 2; ++t) {
      const int j0 = ch * 64 + t * 32;
      const int jl = t * 32;
      const int drel = j0 - iw;
      // transposed content scores: S^T[j=q*4+r (+16)][i=c], K from LDS
      f32x4 S0 = {0.f, 0.f, 0.f, 0.f}, S1 = {0.f, 0.f, 0.f, 0.f};
      {
        const ushortT* ka = &Ks[cur][jl + c][q * 8];
        S0 = MFMA16(*(const s16x8*)ka, qu0, S0, 0, 0, 0);
        S0 = MFMA16(*(const s16x8*)(ka + 32), qu1, S0, 0, 0, 0);
        const ushortT* ka2 = &Ks[cur][jl + 16 + c][q * 8];
        S1 = MFMA16(*(const s16x8*)ka2, qu0, S1, 0, 0, 0);
        S1 = MFMA16(*(const s16x8*)(ka2 + 32), qu1, S1, 0, 0, 0);
      }
      if (j0 < jt) {                     // ---- phase A: region-1 only ----
        const ushortT* pb1 = Ph + (ptrdiff_t)(drel + SEQ - 16) * DK;
        if (hv1) e[0] = e[2];
        else { e[0] = exp4(band_gemm(pb1, 0, c, q, qv0, qv1)); hv1 = true; }
        e[1] = exp4(band_gemm(pb1, 1, c, q, qv0, qv1));
        e[2] = exp4(band_gemm(pb1, 2, c, q, qv0, qv1));
        WRITE_BAND(e)
        const float* e1r = &E1[w][c][q * 8];
        float4 fA = *(const float4*)e1r, fB = *(const float4*)(e1r + 4);
        float pr[8] = {__expf(S0[0]) * fA.x, __expf(S0[1]) * fA.y,
                       __expf(S0[2]) * fA.z, __expf(S0[3]) * fA.w,
                       __expf(S1[0]) * fB.x, __expf(S1[1]) * fB.y,
                       __expf(S1[2]) * fB.z, __expf(S1[3]) * fB.w};
        PV_FROM(pr, j0)
      } else if (j0 < jt + 64) {         // -- phase B: two-pass E1 select --
        float f1[8], f2[8];
        {  // pass 1: region-1 band
          const ushortT* pb1 = Ph + (ptrdiff_t)(drel + SEQ - 16) * DK;
          f32x4 t1[3];
          t1[0] = exp4(band_gemm(pb1, 0, c, q, qv0, qv1));
          t1[1] = exp4(band_gemm(pb1, 1, c, q, qv0, qv1));
          t1[2] = exp4(band_gemm(pb1, 2, c, q, qv0, qv1));
          WRITE_BAND(t1)
          const float* e1r = &E1[w][c][q * 8];
          float4 aA = *(const float4*)e1r, aB = *(const float4*)(e1r + 4);
          f1[0] = aA.x; f1[1] = aA.y; f1[2] = aA.z; f1[3] = aA.w;
          f1[4] = aB.x; f1[5] = aB.y; f1[6] = aB.z; f1[7] = aB.w;
        }
        {  // pass 2: region-2 band (overwrites E1; same-wave ordering)
          const s16x8 qw0 = *(const s16x8*)(Qvb + (size_t)(c + 1) * DK + q * 8);
          const s16x8 qw1 = *(const s16x8*)(Qvb + (size_t)(c + 1) * DK + 32 + q * 8);
          const ushortT* pb2 = Ph + (ptrdiff_t)(drel - 17) * DK;
          f32x4 t2[3];
          t2[0] = exp4(band_gemm(pb2, 0, c, q, qw0, qw1));
          t2[1] = exp4(band_gemm(pb2, 1, c, q, qw0, qw1));
          t2[2] = exp4(band_gemm(pb2, 2, c, q, qw0, qw1));
          WRITE_BAND(t2)
          const float* e1r = &E1[w][c][q * 8];
          float4 bA = *(const float4*)e1r, bB = *(const float4*)(e1r + 4);
          f2[0] = bA.x; f2[1] = bA.y; f2[2] = bA.z; f2[3] = bA.w;
          f2[4] = bB.x; f2[5] = bB.y; f2[6] = bB.z; f2[7] = bB.w;
        }
        float es[8] = {__expf(S0[0]), __expf(S0[1]), __expf(S0[2]), __expf(S0[3]),
                       __expf(S1[0]), __expf(S1[1]), __expf(S1[2]), __expf(S1[3])};
        float pr[8];
#pragma unroll
        for (int jj = 0; jj < 8; ++jj) {
          const int dlt = drel + joff[jj] - c;
          const float f = (dlt <= 0) ? f1[jj] : ((dlt == 1) ? 1.0f : f2[jj]);
          pr[jj] = es[jj] * f;
        }
        PV_FROM(pr, j0)
      } else {                           // ---- phase C: region-2 only ----
        if (!hv2) {                      // switch band A-operand to Q rows +1
          qv0 = *(const s16x8*)(Qvb + (size_t)(c + 1) * DK + q * 8);
          qv1 = *(const s16x8*)(Qvb + (size_t)(c + 1) * DK + 32 + q * 8);
        }
        const ushortT* pb2 = Ph + (ptrdiff_t)(drel - 17) * DK;
        if (hv2) e[0] = e[2];
        else { e[0] = exp4(band_gemm(pb2, 0, c, q, qv0, qv1)); hv2 = true; }
        e[1] = exp4(band_gemm(pb2, 1, c, q, qv0, qv1));
        e[2] = exp4(band_gemm(pb2, 2, c, q, qv0, qv1));
        WRITE_BAND(e)
        const float* e1r = &E1[w][c][q * 8];
        float4 fA = *(const float4*)e1r, fB = *(const float4*)(e1r + 4);
        float pr[8] = {__expf(S0[0]) * fA.x, __expf(S0[1]) * fA.y,
                       __expf(S0[2]) * fA.z, __expf(S0[3]) * fA.w,
                       __expf(S1[0]) * fB.x, __expf(S1[1]) * fB.y,
                       __expf(S1[2]) * fB.z, __expf(S1[3]) * fB.w};
        PV_FROM(pr, j0)
      }
    }
    if (more) {  // write next chunk into the other buffer (no hazard: disjoint)
      *(uint4*)&Ks[1 - cur][tid >> 3][(tid & 7) * 8] = k0v;
      *(uint4*)&Ks[1 - cur][32 + (tid >> 3)][(tid & 7) * 8] = k1v;
    }
    __syncthreads();   // single barrier: writes visible + all done with cur
  }

  // ---- epilogue (rows exclusive to this wave) ----
  lrow += __shfl_xor(lrow, 16);
  lrow += __shfl_xor(lrow, 32);
  if (q == 0) Lb[w][c] = lrow;
  float inv[4];
#pragma unroll
  for (int r = 0; r < 4; ++r) inv[r] = 1.0f / Lb[w][q * 4 + r];
#pragma unroll
  for (int dt = 0; dt < 4; ++dt)
#pragma unroll
    for (int r = 0; r < 4; ++r) {
      const int i = iw + q * 4 + r;
      ctxb[((size_t)b * SEQ + i) * DM + h * DK + dt * 16 + c] = f2bf(O[dt][r] * inv[r]);
    }
}

extern "C" void kernel_launch(void* const* d_in, const int* in_sizes, int n_in,
                              void* d_out, int out_size, void* d_ws, size_t ws_size,
                              hipStream_t stream) {
  (void)in_sizes; (void)n_in; (void)out_size; (void)ws_size;
  const float* X   = (const float*)d_in[0];
  const float* PE  = (const float*)d_in[1];
  const float* Wq  = (const float*)d_in[2];
  const float* Wk  = (const float*)d_in[3];
  const float* Wv  = (const float*)d_in[4];
  const float* Wo  = (const float*)d_in[5];
  const float* Wp  = (const float*)d_in[6];
  const float* ubv = (const float*)d_in[7];
  const float* vbv = (const float*)d_in[8];

  const size_t NX = (size_t)4 * SEQ * DM;   // 4 Mi
  const size_t NP = (size_t)SEQ * DM;       // 1 Mi
  const size_t NW = (size_t)DM * DM;        // 256 Ki
  ushortT* Xb  = (ushortT*)d_ws;
  ushortT* PEb = Xb + NX;
  ushortT* Wt  = PEb + NP;                  // [Wq^T;Wk^T;Wv^T;Wp^T;Wo^T] bf16
  ushortT* qu  = Wt + 5 * NW;
  ushortT* qv  = qu + NX;
  ushortT* kb  = qv + NX;                   // qw overread from qv lands here: safe
  ushortT* vt  = kb + NX;
  ushortT* pp  = vt + NX;                   // NH*PPAD*DK
  ushortT* ctx = pp + (size_t)NH * PPAD * DK;
  float* outp = (float*)d_out;

  hipLaunchKernelGGL(cast_in, dim3((NX + NP) / 4 / 256), dim3(256), 0, stream, X, PE, Xb, PEb);
  hipLaunchKernelGGL(transpose_w, dim3(16, 16, 5), dim3(32, 8), 0, stream, Wq, Wk, Wv, Wp, Wo, Wt);
  dim3 blk(256);
  hipLaunchKernelGGL(gemm_mfma, dim3(128, 12), blk, 0, stream, Xb, Wt, ubv, vbv,
                     qu, qv, kb, vt, (float*)nullptr, 0);
  hipLaunchKernelGGL(gemm_mfma, dim3(32, 4), blk, 0, stream, PEb, Wt + 3 * NW, ubv, vbv,
                     pp, (ushortT*)nullptr, (ushortT*)nullptr, (ushortT*)nullptr, (float*)nullptr, 3);
  hipLaunchKernelGGL(attn_mfma, dim3(1024), blk, 0, stream, qu, qv, kb, vt, pp, ctx);
  hipLaunchKernelGGL(gemm_mfma, dim3(128, 4), blk, 0, stream, ctx, Wt + 4 * NW, ubv, vbv,
                     (ushortT*)nullptr, (ushortT*)nullptr, (ushortT*)nullptr, (ushortT*)nullptr, outp, 4);
}

// Round 13
// 451.307 us; speedup vs baseline: 1.4189x; 1.4189x over previous
//
#include <hip/hip_runtime.h>
#include <hip/hip_bf16.h>
#include <math.h>

#define SEQ 2048
#define NH 8
#define DK 64
#define DM 512
#define RSCALE 0.125f
#define PPAD (SEQ + 128)
#define POFF 64
#define KSTR 72   // K LDS row stride (bf16 el): 144B = 16B-aligned, 2-way banks
#define PSTR 36   // E1 LDS row stride (f32)

typedef unsigned short ushortT;
typedef short s16x8 __attribute__((ext_vector_type(8)));
typedef float f32x4 __attribute__((ext_vector_type(4)));

#define MFMA16 __builtin_amdgcn_mfma_f32_16x16x32_bf16

static __device__ __forceinline__ ushortT f2bf(float x) {
  __hip_bfloat16 h = __float2bfloat16(x);
  ushortT u;
  __builtin_memcpy(&u, &h, 2);
  return u;
}

static __device__ __forceinline__ f32x4 exp4(f32x4 g) {
  f32x4 r;
  r[0] = __expf(g[0]); r[1] = __expf(g[1]);
  r[2] = __expf(g[2]); r[3] = __expf(g[3]);
  return r;
}

static __device__ __forceinline__ s16x8 pack8(const float* p) {
  ushortT u[8];
#pragma unroll
  for (int i = 0; i < 8; ++i) u[i] = f2bf(p[i]);
  s16x8 out;
  __builtin_memcpy(&out, u, 16);
  return out;
}

// pi^-1: j-local column -> A-frag k-slot  (pi(q*8+jj) = jj<4 ? 4q+jj : 16+4q+jj-4)
static __device__ __forceinline__ int pinv(int j) {
  return (j < 16) ? ((j >> 2) * 8 + (j & 3)) : (((j >> 2) - 4) * 8 + 4 + (j & 3));
}

// ---- cast X (4M el) and PE (1M el) to bf16, vectorized x4 ----
__global__ __launch_bounds__(256)
void cast_in(const float* __restrict__ X, const float* __restrict__ PE,
             ushortT* __restrict__ Xb, ushortT* __restrict__ PEb) {
  const size_t i4 = (size_t)blockIdx.x * 256 + threadIdx.x;
  const size_t NX = (size_t)4 * SEQ * DM / 4;
  const float4 v = (i4 < NX) ? *(const float4*)(X + i4 * 4)
                             : *(const float4*)(PE + (i4 - NX) * 4);
  ushortT o[4] = {f2bf(v.x), f2bf(v.y), f2bf(v.z), f2bf(v.w)};
  ushortT* dst = (i4 < NX) ? (Xb + i4 * 4) : (PEb + (i4 - NX) * 4);
  *(ulonglong1*)dst = *(ulonglong1*)o;
}

// ---- transpose 5 weights 512x512 fp32 -> bf16 [n][k], contiguous ----
__global__ __launch_bounds__(256)
void transpose_w(const float* __restrict__ w0, const float* __restrict__ w1,
                 const float* __restrict__ w2, const float* __restrict__ w3,
                 const float* __restrict__ w4, ushortT* __restrict__ out) {
  __shared__ float ts[32][33];
  const int z = blockIdx.z;
  const float* w = (z == 0) ? w0 : (z == 1) ? w1 : (z == 2) ? w2 : (z == 3) ? w3 : w4;
  ushortT* o = out + (size_t)z * DM * DM;
  const int k0 = blockIdx.x * 32, n0 = blockIdx.y * 32;
  const int tx = threadIdx.x, ty = threadIdx.y;
#pragma unroll
  for (int i = 0; i < 4; ++i)
    ts[ty + i * 8][tx] = w[(size_t)(k0 + ty + i * 8) * DM + n0 + tx];
  __syncthreads();
#pragma unroll
  for (int i = 0; i < 4; ++i)
    o[(size_t)(n0 + ty + i * 8) * DM + k0 + tx] = f2bf(ts[tx][ty + i * 8]);
}

// ---- bf16 MFMA GEMM ----
// mode 0: fused QKV, Bt = [Wq^T;Wk^T;Wv^T] (N=1536). z=gn>>9 selects output:
//   z0: qu/qv = bf16((acc+u/v)*RSCALE) [bh][s][d]; z1: kb [bh][s][d];
//   z2: vt [bh][d][s'] with within-32 pi-permuted column s'
// mode 3 (P): qu <- bf16 [h][POFF+s][d];  mode 4: of fp32 [m][n]
__global__ __launch_bounds__(256)
void gemm_mfma(const ushortT* __restrict__ A, const ushortT* __restrict__ Bt,
               const float* __restrict__ ubv, const float* __restrict__ vbv,
               ushortT* __restrict__ qu, ushortT* __restrict__ qv,
               ushortT* __restrict__ kb, ushortT* __restrict__ vt,
               float* __restrict__ of, int mode) {
  const int w = threadIdx.x >> 6, lane = threadIdx.x & 63;
  const int c = lane & 15, q = lane >> 4;
  const int m0 = blockIdx.x * 64;
  const int n0 = blockIdx.y * 128 + w * 32;

  const ushortT* Ab = A + (size_t)m0 * DM + q * 8;
  const ushortT* Bb = Bt + (size_t)n0 * DM + q * 8;

  f32x4 acc[4][2];
#pragma unroll
  for (int mt = 0; mt < 4; ++mt)
#pragma unroll
    for (int nt = 0; nt < 2; ++nt) acc[mt][nt] = (f32x4){0.f, 0.f, 0.f, 0.f};

  s16x8 a[4], bfr[2], an[4], bn[2];
#pragma unroll
  for (int mt = 0; mt < 4; ++mt) a[mt] = *(const s16x8*)(Ab + (size_t)(mt * 16 + c) * DM);
#pragma unroll
  for (int nt = 0; nt < 2; ++nt) bfr[nt] = *(const s16x8*)(Bb + (size_t)(nt * 16 + c) * DM);

  for (int k0 = 0; k0 < DM; k0 += 32) {
    if (k0 + 32 < DM) {
#pragma unroll
      for (int mt = 0; mt < 4; ++mt)
        an[mt] = *(const s16x8*)(Ab + (size_t)(mt * 16 + c) * DM + k0 + 32);
#pragma unroll
      for (int nt = 0; nt < 2; ++nt)
        bn[nt] = *(const s16x8*)(Bb + (size_t)(nt * 16 + c) * DM + k0 + 32);
    }
#pragma unroll
    for (int mt = 0; mt < 4; ++mt)
#pragma unroll
      for (int nt = 0; nt < 2; ++nt)
        acc[mt][nt] = MFMA16(a[mt], bfr[nt], acc[mt][nt], 0, 0, 0);
#pragma unroll
    for (int mt = 0; mt < 4; ++mt) a[mt] = an[mt];
#pragma unroll
    for (int nt = 0; nt < 2; ++nt) bfr[nt] = bn[nt];
  }

#pragma unroll
  for (int mt = 0; mt < 4; ++mt)
#pragma unroll
    for (int nt = 0; nt < 2; ++nt)
#pragma unroll
      for (int r = 0; r < 4; ++r) {
        const int gm = m0 + mt * 16 + q * 4 + r;
        const int gn = n0 + nt * 16 + c;
        const float v = acc[mt][nt][r];
        const int bb = gm >> 11, s = gm & (SEQ - 1);
        if (mode == 0) {
          const int z = gn >> 9, gn5 = gn & 511;
          const int h = gn5 >> 6, d = gn5 & 63;
          if (z == 0) {
            const size_t base = (((size_t)bb * NH + h) * SEQ + s) * DK + d;
            qu[base] = f2bf((v + ubv[gn5]) * RSCALE);
            qv[base] = f2bf((v + vbv[gn5]) * RSCALE);
          } else if (z == 1) {
            kb[(((size_t)bb * NH + h) * SEQ + s) * DK + d] = f2bf(v);
          } else {
            const int s_il = (s & ~31) | pinv(s & 31);
            vt[(((size_t)bb * NH + h) * DK + d) * SEQ + s_il] = f2bf(v);
          }
        } else if (mode == 3) {
          const int h = gn >> 6, d = gn & 63;
          qu[((size_t)h * PPAD + POFF + gm) * DK + d] = f2bf(v);
        } else {
          of[(size_t)gm * DM + gn] = v;
        }
      }
}

// ---- band GEMM helper: G = Qrow-block x P[tile*16 .. +15]  (P from L2) ----
static __device__ __forceinline__ f32x4 band_gemm(const ushortT* pb, int tile,
                                                  int c, int q, s16x8 a0, s16x8 a1) {
  const ushortT* pc = pb + (ptrdiff_t)(tile * 16 + c) * DK + q * 8;
  f32x4 G = {0.f, 0.f, 0.f, 0.f};
  G = MFMA16(a0, *(const s16x8*)pc, G, 0, 0, 0);
  G = MFMA16(a1, *(const s16x8*)(pc + 32), G, 0, 0, 0);
  return G;
}

// ---- MFMA flash relative attention: dbuf LDS K, global V, slim LDS ----
// __launch_bounds__(256,4): VGPR cap 128 (kernel needs ~90-100).
// (256,5) capped at ~96 and SPILLED: VGPR_Count=48, WRITE_SIZE 288MB (r11).
__global__ __launch_bounds__(256, 4)
void attn_mfma(const ushortT* __restrict__ Qu, const ushortT* __restrict__ Qv,
               const ushortT* __restrict__ Kb, const ushortT* __restrict__ Vt,
               const ushortT* __restrict__ Pp, ushortT* __restrict__ ctxb) {
  const int n = blockIdx.x;
  const int xcd = n & 7, idx = n >> 3;      // XCD x serves h=x (L2 locality)
  const int b = idx >> 5, iblk = idx & 31;
  const int h = xcd, bh = b * 8 + h;
  const int tid = threadIdx.x;
  const int w = tid >> 6, lane = tid & 63;
  const int c = lane & 15, q = lane >> 4;
  const int i0 = iblk * 64;
  const int iw = i0 + w * 16;

  __shared__ ushortT Ks[2][64][KSTR];
  __shared__ float E1[4][16][PSTR];   // exp(G) band, pi-slotted cols (per wave)
  __shared__ float Lb[4][16];

  const ushortT* Qub = Qu + ((size_t)bh * SEQ + iw) * DK;
  const ushortT* Qvb = Qv + ((size_t)bh * SEQ + iw) * DK;
  const ushortT* Kbh = Kb + (size_t)bh * SEQ * DK;
  const ushortT* Vbh = Vt + (size_t)bh * DK * SEQ;
  const ushortT* Ph  = Pp + ((size_t)h * PPAD + POFF) * DK;

  const s16x8 qu0 = *(const s16x8*)(Qub + (size_t)c * DK + q * 8);
  const s16x8 qu1 = *(const s16x8*)(Qub + (size_t)c * DK + 32 + q * 8);
  s16x8 qv0 = *(const s16x8*)(Qvb + (size_t)c * DK + q * 8);
  s16x8 qv1 = *(const s16x8*)(Qvb + (size_t)c * DK + 32 + q * 8);

  // per-slot j-local offsets: pi(q*8+jj)
  int joff[8];
#pragma unroll
  for (int jj = 0; jj < 8; ++jj)
    joff[jj] = (jj < 4) ? (4 * q + jj) : (16 + 4 * q + (jj - 4));

  f32x4 O[4];
#pragma unroll
  for (int r = 0; r < 4; ++r) O[r] = (f32x4){0.f, 0.f, 0.f, 0.f};
  float lrow = 0.f;
  f32x4 e[3];
  bool hv1 = false, hv2 = false;
  const int jt = iw & ~31;
  const int m_w = q * 4;

  // ---- prologue: stage chunk 0 into Ks[0] ----
  {
    uint4 k0v = *(const uint4*)(Kbh + tid * 8);
    uint4 k1v = *(const uint4*)(Kbh + 2048 + tid * 8);
    *(uint4*)&Ks[0][tid >> 3][(tid & 7) * 8] = k0v;
    *(uint4*)&Ks[0][32 + (tid >> 3)][(tid & 7) * 8] = k1v;
  }
  __syncthreads();

#define WRITE_BAND(ev)                                                        \
  _Pragma("unroll")                                                           \
  for (int t = 0; t < 3; ++t)                                                 \
    _Pragma("unroll")                                                         \
    for (int r = 0; r < 4; ++r) {                                             \
      const int kcol = t * 16 + c + (m_w + r) - 15;                           \
      if (kcol >= 0 && kcol < 32) E1[w][m_w + r][pinv(kcol)] = (ev)[t][r];    \
    }

#define PV_FROM(pr, j0g)                                                      \
  {                                                                           \
    lrow += pr[0] + pr[1] + pr[2] + pr[3] + pr[4] + pr[5] + pr[6] + pr[7];    \
    const s16x8 pa = pack8(pr);                                               \
    _Pragma("unroll")                                                         \
    for (int dt = 0; dt < 4; ++dt) {                                          \
      const s16x8 vb = *(const s16x8*)(Vbh + (size_t)(dt * 16 + c) * SEQ + (j0g) + q * 8); \
      O[dt] = MFMA16(pa, vb, O[dt], 0, 0, 0);                                 \
    }                                                                         \
  }

  for (int ch = 0; ch < 32; ++ch) {
    const int cur = ch & 1;
    const bool more = (ch + 1) < 32;
    uint4 k0v, k1v;
    if (more) {  // prefetch next K chunk (latency overlaps compute)
      const ushortT* gk = Kbh + (size_t)(ch + 1) * 64 * DK;
      k0v = *(const uint4*)(gk + tid * 8);
      k1v = *(const uint4*)(gk + 2048 + tid * 8);
    }
#pragma unroll
    for (int t = 0; t < 2; ++t) {
      const int j0 = ch * 64 + t * 32;
      const int jl = t * 32;
      const int drel = j0 - iw;
      // transposed content scores: S^T[j=q*4+r (+16)][i=c], K from LDS
      f32x4 S0 = {0.f, 0.f, 0.f, 0.f}, S1 = {0.f, 0.f, 0.f, 0.f};
      {
        const ushortT* ka = &Ks[cur][jl + c][q * 8];
        S0 = MFMA16(*(const s16x8*)ka, qu0, S0, 0, 0, 0);
        S0 = MFMA16(*(const s16x8*)(ka + 32), qu1, S0, 0, 0, 0);
        const ushortT* ka2 = &Ks[cur][jl + 16 + c][q * 8];
        S1 = MFMA16(*(const s16x8*)ka2, qu0, S1, 0, 0, 0);
        S1 = MFMA16(*(const s16x8*)(ka2 + 32), qu1, S1, 0, 0, 0);
      }
      if (j0 < jt) {                     // ---- phase A: region-1 only ----
        const ushortT* pb1 = Ph + (ptrdiff_t)(drel + SEQ - 16) * DK;
        if (hv1) e[0] = e[2];
        else { e[0] = exp4(band_gemm(pb1, 0, c, q, qv0, qv1)); hv1 = true; }
        e[1] = exp4(band_gemm(pb1, 1, c, q, qv0, qv1));
        e[2] = exp4(band_gemm(pb1, 2, c, q, qv0, qv1));
        WRITE_BAND(e)
        const float* e1r = &E1[w][c][q * 8];
        float4 fA = *(const float4*)e1r, fB = *(const float4*)(e1r + 4);
        float pr[8] = {__expf(S0[0]) * fA.x, __expf(S0[1]) * fA.y,
                       __expf(S0[2]) * fA.z, __expf(S0[3]) * fA.w,
                       __expf(S1[0]) * fB.x, __expf(S1[1]) * fB.y,
                       __expf(S1[2]) * fB.z, __expf(S1[3]) * fB.w};
        PV_FROM(pr, j0)
      } else if (j0 < jt + 64) {         // -- phase B: two-pass E1 select --
        float f1[8], f2[8];
        {  // pass 1: region-1 band
          const ushortT* pb1 = Ph + (ptrdiff_t)(drel + SEQ - 16) * DK;
          f32x4 t1[3];
          t1[0] = exp4(band_gemm(pb1, 0, c, q, qv0, qv1));
          t1[1] = exp4(band_gemm(pb1, 1, c, q, qv0, qv1));
          t1[2] = exp4(band_gemm(pb1, 2, c, q, qv0, qv1));
          WRITE_BAND(t1)
          const float* e1r = &E1[w][c][q * 8];
          float4 aA = *(const float4*)e1r, aB = *(const float4*)(e1r + 4);
          f1[0] = aA.x; f1[1] = aA.y; f1[2] = aA.z; f1[3] = aA.w;
          f1[4] = aB.x; f1[5] = aB.y; f1[6] = aB.z; f1[7] = aB.w;
        }
        {  // pass 2: region-2 band (overwrites E1; same-wave ordering)
          const s16x8 qw0 = *(const s16x8*)(Qvb + (size_t)(c + 1) * DK + q * 8);
          const s16x8 qw1 = *(const s16x8*)(Qvb + (size_t)(c + 1) * DK + 32 + q * 8);
          const ushortT* pb2 = Ph + (ptrdiff_t)(drel - 17) * DK;
          f32x4 t2[3];
          t2[0] = exp4(band_gemm(pb2, 0, c, q, qw0, qw1));
          t2[1] = exp4(band_gemm(pb2, 1, c, q, qw0, qw1));
          t2[2] = exp4(band_gemm(pb2, 2, c, q, qw0, qw1));
          WRITE_BAND(t2)
          const float* e1r = &E1[w][c][q * 8];
          float4 bA = *(const float4*)e1r, bB = *(const float4*)(e1r + 4);
          f2[0] = bA.x; f2[1] = bA.y; f2[2] = bA.z; f2[3] = bA.w;
          f2[4] = bB.x; f2[5] = bB.y; f2[6] = bB.z; f2[7] = bB.w;
        }
        float es[8] = {__expf(S0[0]), __expf(S0[1]), __expf(S0[2]), __expf(S0[3]),
                       __expf(S1[0]), __expf(S1[1]), __expf(S1[2]), __expf(S1[3])};
        float pr[8];
#pragma unroll
        for (int jj = 0; jj < 8; ++jj) {
          const int dlt = drel + joff[jj] - c;
          const float f = (dlt <= 0) ? f1[jj] : ((dlt == 1) ? 1.0f : f2[jj]);
          pr[jj] = es[jj] * f;
        }
        PV_FROM(pr, j0)
      } else {                           // ---- phase C: region-2 only ----
        if (!hv2) {                      // switch band A-operand to Q rows +1
          qv0 = *(const s16x8*)(Qvb + (size_t)(c + 1) * DK + q * 8);
          qv1 = *(const s16x8*)(Qvb + (size_t)(c + 1) * DK + 32 + q * 8);
        }
        const ushortT* pb2 = Ph + (ptrdiff_t)(drel - 17) * DK;
        if (hv2) e[0] = e[2];
        else { e[0] = exp4(band_gemm(pb2, 0, c, q, qv0, qv1)); hv2 = true; }
        e[1] = exp4(band_gemm(pb2, 1, c, q, qv0, qv1));
        e[2] = exp4(band_gemm(pb2, 2, c, q, qv0, qv1));
        WRITE_BAND(e)
        const float* e1r = &E1[w][c][q * 8];
        float4 fA = *(const float4*)e1r, fB = *(const float4*)(e1r + 4);
        float pr[8] = {__expf(S0[0]) * fA.x, __expf(S0[1]) * fA.y,
                       __expf(S0[2]) * fA.z, __expf(S0[3]) * fA.w,
                       __expf(S1[0]) * fB.x, __expf(S1[1]) * fB.y,
                       __expf(S1[2]) * fB.z, __expf(S1[3]) * fB.w};
        PV_FROM(pr, j0)
      }
    }
    if (more) {  // write next chunk into the other buffer (no hazard: disjoint)
      *(uint4*)&Ks[1 - cur][tid >> 3][(tid & 7) * 8] = k0v;
      *(uint4*)&Ks[1 - cur][32 + (tid >> 3)][(tid & 7) * 8] = k1v;
    }
    __syncthreads();   // single barrier: writes visible + all done with cur
  }

  // ---- epilogue (rows exclusive to this wave) ----
  lrow += __shfl_xor(lrow, 16);
  lrow += __shfl_xor(lrow, 32);
  if (q == 0) Lb[w][c] = lrow;
  float inv[4];
#pragma unroll
  for (int r = 0; r < 4; ++r) inv[r] = 1.0f / Lb[w][q * 4 + r];
#pragma unroll
  for (int dt = 0; dt < 4; ++dt)
#pragma unroll
    for (int r = 0; r < 4; ++r) {
      const int i = iw + q * 4 + r;
      ctxb[((size_t)b * SEQ + i) * DM + h * DK + dt * 16 + c] = f2bf(O[dt][r] * inv[r]);
    }
}

extern "C" void kernel_launch(void* const* d_in, const int* in_sizes, int n_in,
                              void* d_out, int out_size, void* d_ws, size_t ws_size,
                              hipStream_t stream) {
  (void)in_sizes; (void)n_in; (void)out_size; (void)ws_size;
  const float* X   = (const float*)d_in[0];
  const float* PE  = (const float*)d_in[1];
  const float* Wq  = (const float*)d_in[2];
  const float* Wk  = (const float*)d_in[3];
  const float* Wv  = (const float*)d_in[4];
  const float* Wo  = (const float*)d_in[5];
  const float* Wp  = (const float*)d_in[6];
  const float* ubv = (const float*)d_in[7];
  const float* vbv = (const float*)d_in[8];

  const size_t NX = (size_t)4 * SEQ * DM;   // 4 Mi
  const size_t NP = (size_t)SEQ * DM;       // 1 Mi
  const size_t NW = (size_t)DM * DM;        // 256 Ki
  ushortT* Xb  = (ushortT*)d_ws;
  ushortT* PEb = Xb + NX;
  ushortT* Wt  = PEb + NP;                  // [Wq^T;Wk^T;Wv^T;Wp^T;Wo^T] bf16
  ushortT* qu  = Wt + 5 * NW;
  ushortT* qv  = qu + NX;
  ushortT* kb  = qv + NX;                   // qw overread from qv lands here: safe
  ushortT* vt  = kb + NX;
  ushortT* pp  = vt + NX;                   // NH*PPAD*DK
  ushortT* ctx = pp + (size_t)NH * PPAD * DK;
  float* outp = (float*)d_out;

  hipLaunchKernelGGL(cast_in, dim3((NX + NP) / 4 / 256), dim3(256), 0, stream, X, PE, Xb, PEb);
  hipLaunchKernelGGL(transpose_w, dim3(16, 16, 5), dim3(32, 8), 0, stream, Wq, Wk, Wv, Wp, Wo, Wt);
  dim3 blk(256);
  hipLaunchKernelGGL(gemm_mfma, dim3(128, 12), blk, 0, stream, Xb, Wt, ubv, vbv,
                     qu, qv, kb, vt, (float*)nullptr, 0);
  hipLaunchKernelGGL(gemm_mfma, dim3(32, 4), blk, 0, stream, PEb, Wt + 3 * NW, ubv, vbv,
                     pp, (ushortT*)nullptr, (ushortT*)nullptr, (ushortT*)nullptr, (float*)nullptr, 3);
  hipLaunchKernelGGL(attn_mfma, dim3(1024), blk, 0, stream, qu, qv, kb, vt, pp, ctx);
  hipLaunchKernelGGL(gemm_mfma, dim3(128, 4), blk, 0, stream, ctx, Wt + 4 * NW, ubv, vbv,
                     (ushortT*)nullptr, (ushortT*)nullptr, (ushortT*)nullptr, (ushortT*)nullptr, outp, 4);
}

// Round 14
// 370.386 us; speedup vs baseline: 1.7289x; 1.2185x over previous
//
#include <hip/hip_runtime.h>
#include <hip/hip_bf16.h>
#include <math.h>

#define SEQ 2048
#define NH 8
#define DK 64
#define DM 512
#define RSCALE 0.125f
#define PPAD (SEQ + 128)
#define POFF 64
#define KSTR 72   // K/V LDS row stride (bf16 el): 144B = 16B-aligned, 2-way banks
#define PSTR 36   // E1/E2 LDS row stride (f32)
#define ASTR 34   // GEMM LDS row stride (bf16 el): 68B -> 17-bank row offset

typedef unsigned short ushortT;
typedef short s16x8 __attribute__((ext_vector_type(8)));
typedef float f32x4 __attribute__((ext_vector_type(4)));

#define MFMA16 __builtin_amdgcn_mfma_f32_16x16x32_bf16

static __device__ __forceinline__ ushortT f2bf(float x) {
  __hip_bfloat16 h = __float2bfloat16(x);
  ushortT u;
  __builtin_memcpy(&u, &h, 2);
  return u;
}

static __device__ __forceinline__ f32x4 exp4(f32x4 g) {
  f32x4 r;
  r[0] = __expf(g[0]); r[1] = __expf(g[1]);
  r[2] = __expf(g[2]); r[3] = __expf(g[3]);
  return r;
}

static __device__ __forceinline__ s16x8 pack8(const float* p) {
  ushortT u[8];
#pragma unroll
  for (int i = 0; i < 8; ++i) u[i] = f2bf(p[i]);
  s16x8 out;
  __builtin_memcpy(&out, u, 16);
  return out;
}

// pi^-1: j-local column -> A-frag k-slot  (pi(q*8+jj) = jj<4 ? 4q+jj : 16+4q+jj-4)
static __device__ __forceinline__ int pinv(int j) {
  return (j < 16) ? ((j >> 2) * 8 + (j & 3)) : (((j >> 2) - 4) * 8 + 4 + (j & 3));
}

// ---- cast X (4M el) and PE (1M el) to bf16, vectorized x4 ----
__global__ __launch_bounds__(256)
void cast_in(const float* __restrict__ X, const float* __restrict__ PE,
             ushortT* __restrict__ Xb, ushortT* __restrict__ PEb) {
  const size_t i4 = (size_t)blockIdx.x * 256 + threadIdx.x;
  const size_t NX = (size_t)4 * SEQ * DM / 4;
  const float4 v = (i4 < NX) ? *(const float4*)(X + i4 * 4)
                             : *(const float4*)(PE + (i4 - NX) * 4);
  ushortT o[4] = {f2bf(v.x), f2bf(v.y), f2bf(v.z), f2bf(v.w)};
  ushortT* dst = (i4 < NX) ? (Xb + i4 * 4) : (PEb + (i4 - NX) * 4);
  *(ulonglong1*)dst = *(ulonglong1*)o;
}

// ---- transpose 5 weights 512x512 fp32 -> bf16 [n][k], contiguous ----
__global__ __launch_bounds__(256)
void transpose_w(const float* __restrict__ w0, const float* __restrict__ w1,
                 const float* __restrict__ w2, const float* __restrict__ w3,
                 const float* __restrict__ w4, ushortT* __restrict__ out) {
  __shared__ float ts[32][33];
  const int z = blockIdx.z;
  const float* w = (z == 0) ? w0 : (z == 1) ? w1 : (z == 2) ? w2 : (z == 3) ? w3 : w4;
  ushortT* o = out + (size_t)z * DM * DM;
  const int k0 = blockIdx.x * 32, n0 = blockIdx.y * 32;
  const int tx = threadIdx.x, ty = threadIdx.y;
#pragma unroll
  for (int i = 0; i < 4; ++i)
    ts[ty + i * 8][tx] = w[(size_t)(k0 + ty + i * 8) * DM + n0 + tx];
  __syncthreads();
#pragma unroll
  for (int i = 0; i < 4; ++i)
    o[(size_t)(n0 + ty + i * 8) * DM + k0 + tx] = f2bf(ts[tx][ty + i * 8]);
}

// ---- LDS-staged bf16 MFMA GEMM, 128x128 tile, BK=32 (m93 pattern) ----
// A [M][512] bf16 row-major; Bt [N][512] bf16 (row n = output col n over k).
// Wave w -> 64x64 quadrant (wm=w>>1, wn=w&1), 4x4 acc of 16x16 tiles.
// mode 0: fused QKV (N=1536): z0 qu/qv=bf16((acc+u/v)*RSCALE) [bh][s][d];
//   z1 kb [bh][s][d]; z2 vt [bh][d][s'] with pi-permuted s'.
// mode 3 (P): qu <- bf16 [h][POFF+s][d];  mode 4: of fp32 [m][n]
__global__ __launch_bounds__(256)
void gemm_mfma(const ushortT* __restrict__ A, const ushortT* __restrict__ Bt,
               const float* __restrict__ ubv, const float* __restrict__ vbv,
               ushortT* __restrict__ qu, ushortT* __restrict__ qv,
               ushortT* __restrict__ kb, ushortT* __restrict__ vt,
               float* __restrict__ of, int mode) {
  __shared__ ushortT As[128][ASTR];
  __shared__ ushortT Bs[128][ASTR];
  const int tid = threadIdx.x;
  const int w = tid >> 6, lane = tid & 63;
  const int c = lane & 15, q = lane >> 4;
  const int wm = w >> 1, wn = w & 1;
  const int m0 = blockIdx.x * 128, n0 = blockIdx.y * 128;
  const int lr = tid >> 1, lh = (tid & 1) * 16;  // load row 0..127, k-half

  f32x4 acc[4][4];
#pragma unroll
  for (int mt = 0; mt < 4; ++mt)
#pragma unroll
    for (int nt = 0; nt < 4; ++nt) acc[mt][nt] = (f32x4){0.f, 0.f, 0.f, 0.f};

  const ushortT* Ar = A + (size_t)(m0 + lr) * DM + lh;
  const ushortT* Br = Bt + (size_t)(n0 + lr) * DM + lh;
  uint4 a0 = *(const uint4*)(Ar);
  uint4 a1 = *(const uint4*)(Ar + 8);
  uint4 b0 = *(const uint4*)(Br);
  uint4 b1 = *(const uint4*)(Br + 8);

  for (int k0 = 0; k0 < DM; k0 += 32) {
    __syncthreads();                       // prior compute done reading LDS
    *(uint4*)&As[lr][lh] = a0; *(uint4*)&As[lr][lh + 8] = a1;
    *(uint4*)&Bs[lr][lh] = b0; *(uint4*)&Bs[lr][lh + 8] = b1;
    __syncthreads();                       // staging visible
    if (k0 + 32 < DM) {                    // prefetch next slab (overlaps MFMA)
      a0 = *(const uint4*)(Ar + k0 + 32);
      a1 = *(const uint4*)(Ar + k0 + 40);
      b0 = *(const uint4*)(Br + k0 + 32);
      b1 = *(const uint4*)(Br + k0 + 40);
    }
    s16x8 af[4], bf[4];
#pragma unroll
    for (int mt = 0; mt < 4; ++mt)
      af[mt] = *(const s16x8*)&As[wm * 64 + mt * 16 + c][q * 8];
#pragma unroll
    for (int nt = 0; nt < 4; ++nt)
      bf[nt] = *(const s16x8*)&Bs[wn * 64 + nt * 16 + c][q * 8];
#pragma unroll
    for (int mt = 0; mt < 4; ++mt)
#pragma unroll
      for (int nt = 0; nt < 4; ++nt)
        acc[mt][nt] = MFMA16(af[mt], bf[nt], acc[mt][nt], 0, 0, 0);
  }

#pragma unroll
  for (int mt = 0; mt < 4; ++mt)
#pragma unroll
    for (int nt = 0; nt < 4; ++nt)
#pragma unroll
      for (int r = 0; r < 4; ++r) {
        const int gm = m0 + wm * 64 + mt * 16 + q * 4 + r;
        const int gn = n0 + wn * 64 + nt * 16 + c;
        const float v = acc[mt][nt][r];
        const int bb = gm >> 11, s = gm & (SEQ - 1);
        if (mode == 0) {
          const int z = gn >> 9, gn5 = gn & 511;
          const int h = gn5 >> 6, d = gn5 & 63;
          if (z == 0) {
            const size_t base = (((size_t)bb * NH + h) * SEQ + s) * DK + d;
            qu[base] = f2bf((v + ubv[gn5]) * RSCALE);
            qv[base] = f2bf((v + vbv[gn5]) * RSCALE);
          } else if (z == 1) {
            kb[(((size_t)bb * NH + h) * SEQ + s) * DK + d] = f2bf(v);
          } else {
            const int s_il = (s & ~31) | pinv(s & 31);
            vt[(((size_t)bb * NH + h) * DK + d) * SEQ + s_il] = f2bf(v);
          }
        } else if (mode == 3) {
          const int h = gn >> 6, d = gn & 63;
          qu[((size_t)h * PPAD + POFF + gm) * DK + d] = f2bf(v);
        } else {
          of[(size_t)gm * DM + gn] = v;
        }
      }
}

// ---- band GEMM helper: G = Qrow-block x P[tile*16 .. +15]  (P from L2) ----
static __device__ __forceinline__ f32x4 band_gemm(const ushortT* pb, int tile,
                                                  int c, int q, s16x8 a0, s16x8 a1) {
  const ushortT* pc = pb + (ptrdiff_t)(tile * 16 + c) * DK + q * 8;
  f32x4 G = {0.f, 0.f, 0.f, 0.f};
  G = MFMA16(a0, *(const s16x8*)pc, G, 0, 0, 0);
  G = MFMA16(a1, *(const s16x8*)(pc + 32), G, 0, 0, 0);
  return G;
}

// ---- MFMA flash relative attention: LDS-staged K/V, TRANSPOSED scores ----
// (round-10 structure verbatim: measured 233.8 us, VGPR 84, no spill)
__global__ __launch_bounds__(256, 3)
void attn_mfma(const ushortT* __restrict__ Qu, const ushortT* __restrict__ Qv,
               const ushortT* __restrict__ Kb, const ushortT* __restrict__ Vt,
               const ushortT* __restrict__ Pp, ushortT* __restrict__ ctxb) {
  const int n = blockIdx.x;
  const int xcd = n & 7, idx = n >> 3;      // XCD x serves h=x (L2 locality)
  const int b = idx >> 5, iblk = idx & 31;
  const int h = xcd, bh = b * 8 + h;
  const int tid = threadIdx.x;
  const int w = tid >> 6, lane = tid & 63;
  const int c = lane & 15, q = lane >> 4;
  const int i0 = iblk * 64;
  const int iw = i0 + w * 16;

  __shared__ ushortT Ks[64][KSTR];
  __shared__ ushortT Vs[64][KSTR];
  __shared__ float E1[4][16][PSTR];   // exp(G) region-1 band, pi-slotted cols
  __shared__ float E2[4][16][PSTR];   // exp(G) region-2 band (phase B only)
  __shared__ float Lb[4][16];

  const ushortT* Qub = Qu + ((size_t)bh * SEQ + iw) * DK;
  const ushortT* Qvb = Qv + ((size_t)bh * SEQ + iw) * DK;
  const ushortT* Kbh = Kb + (size_t)bh * SEQ * DK;
  const ushortT* Vbh = Vt + (size_t)bh * DK * SEQ;
  const ushortT* Ph  = Pp + ((size_t)h * PPAD + POFF) * DK;

  const s16x8 qu0 = *(const s16x8*)(Qub + (size_t)c * DK + q * 8);
  const s16x8 qu1 = *(const s16x8*)(Qub + (size_t)c * DK + 32 + q * 8);
  s16x8 qv0 = *(const s16x8*)(Qvb + (size_t)c * DK + q * 8);
  s16x8 qv1 = *(const s16x8*)(Qvb + (size_t)c * DK + 32 + q * 8);

  // per-slot j-local offsets: pi(q*8+jj)
  int joff[8];
#pragma unroll
  for (int jj = 0; jj < 8; ++jj)
    joff[jj] = (jj < 4) ? (4 * q + jj) : (16 + 4 * q + (jj - 4));

  f32x4 O[4];
#pragma unroll
  for (int r = 0; r < 4; ++r) O[r] = (f32x4){0.f, 0.f, 0.f, 0.f};
  float lrow = 0.f;
  f32x4 e[3];
  bool hv1 = false, hv2 = false;
  const int jt = iw & ~31;
  const int m_w = q * 4;

  // ---- prologue: stage chunk 0 ----
  {
    const ushortT* gk = Kbh;
    uint4 k0v = *(const uint4*)(gk + tid * 8);
    uint4 k1v = *(const uint4*)(gk + 2048 + tid * 8);
    const ushortT* gv = Vbh + (size_t)(tid >> 2) * SEQ + (tid & 3) * 16;
    uint4 v0v = *(const uint4*)gv;
    uint4 v1v = *(const uint4*)(gv + 8);
    *(uint4*)&Ks[tid >> 3][(tid & 7) * 8] = k0v;
    *(uint4*)&Ks[32 + (tid >> 3)][(tid & 7) * 8] = k1v;
    *(uint4*)&Vs[tid >> 2][(tid & 3) * 16] = v0v;
    *(uint4*)&Vs[tid >> 2][(tid & 3) * 16 + 8] = v1v;
  }
  __syncthreads();

#define WRITE_BAND(ARR, ev)                                                   \
  _Pragma("unroll")                                                           \
  for (int t = 0; t < 3; ++t)                                                 \
    _Pragma("unroll")                                                         \
    for (int r = 0; r < 4; ++r) {                                             \
      const int kcol = t * 16 + c + (m_w + r) - 15;                           \
      if (kcol >= 0 && kcol < 32) ARR[w][m_w + r][pinv(kcol)] = (ev)[t][r];   \
    }

#define PV_FROM(pr, jl)                                                       \
  {                                                                           \
    lrow += pr[0] + pr[1] + pr[2] + pr[3] + pr[4] + pr[5] + pr[6] + pr[7];    \
    const s16x8 pa = pack8(pr);                                               \
    _Pragma("unroll")                                                         \
    for (int dt = 0; dt < 4; ++dt) {                                          \
      const s16x8 vb = *(const s16x8*)&Vs[dt * 16 + c][(jl) + q * 8];         \
      O[dt] = MFMA16(pa, vb, O[dt], 0, 0, 0);                                 \
    }                                                                         \
  }

  for (int ch = 0; ch < 32; ++ch) {
    const bool more = (ch + 1) < 32;
    uint4 k0v, k1v, v0v, v1v;
    if (more) {  // prefetch next chunk into registers (overlaps compute)
      const ushortT* gk = Kbh + (size_t)(ch + 1) * 64 * DK;
      k0v = *(const uint4*)(gk + tid * 8);
      k1v = *(const uint4*)(gk + 2048 + tid * 8);
      const ushortT* gv = Vbh + (size_t)(tid >> 2) * SEQ + (ch + 1) * 64 + (tid & 3) * 16;
      v0v = *(const uint4*)gv;
      v1v = *(const uint4*)(gv + 8);
    }
#pragma unroll
    for (int t = 0; t < 2; ++t) {
      const int j0 = ch * 64 + t * 32;
      const int jl = t * 32;
      const int drel = j0 - iw;
      // transposed content scores: S^T[j=q*4+r (+16)][i=c], K from LDS
      f32x4 S0 = {0.f, 0.f, 0.f, 0.f}, S1 = {0.f, 0.f, 0.f, 0.f};
      {
        const ushortT* ka = &Ks[jl + c][q * 8];
        S0 = MFMA16(*(const s16x8*)ka, qu0, S0, 0, 0, 0);
        S0 = MFMA16(*(const s16x8*)(ka + 32), qu1, S0, 0, 0, 0);
        const ushortT* ka2 = &Ks[jl + 16 + c][q * 8];
        S1 = MFMA16(*(const s16x8*)ka2, qu0, S1, 0, 0, 0);
        S1 = MFMA16(*(const s16x8*)(ka2 + 32), qu1, S1, 0, 0, 0);
      }
      if (j0 < jt) {                     // ---- phase A: region-1 only ----
        const ushortT* pb1 = Ph + (ptrdiff_t)(drel + SEQ - 16) * DK;
        if (hv1) e[0] = e[2];
        else { e[0] = exp4(band_gemm(pb1, 0, c, q, qv0, qv1)); hv1 = true; }
        e[1] = exp4(band_gemm(pb1, 1, c, q, qv0, qv1));
        e[2] = exp4(band_gemm(pb1, 2, c, q, qv0, qv1));
        WRITE_BAND(E1, e)
        const float* e1r = &E1[w][c][q * 8];
        float4 fA = *(const float4*)e1r, fB = *(const float4*)(e1r + 4);
        float pr[8] = {__expf(S0[0]) * fA.x, __expf(S0[1]) * fA.y,
                       __expf(S0[2]) * fA.z, __expf(S0[3]) * fA.w,
                       __expf(S1[0]) * fB.x, __expf(S1[1]) * fB.y,
                       __expf(S1[2]) * fB.z, __expf(S1[3]) * fB.w};
        PV_FROM(pr, jl)
      } else if (j0 < jt + 64) {         // ---- phase B: per-slot select ----
        {
          const ushortT* pb1 = Ph + (ptrdiff_t)(drel + SEQ - 16) * DK;
          f32x4 t1[3];
          t1[0] = exp4(band_gemm(pb1, 0, c, q, qv0, qv1));
          t1[1] = exp4(band_gemm(pb1, 1, c, q, qv0, qv1));
          t1[2] = exp4(band_gemm(pb1, 2, c, q, qv0, qv1));
          WRITE_BAND(E1, t1)
        }
        {
          const s16x8 qw0 = *(const s16x8*)(Qvb + (size_t)(c + 1) * DK + q * 8);
          const s16x8 qw1 = *(const s16x8*)(Qvb + (size_t)(c + 1) * DK + 32 + q * 8);
          const ushortT* pb2 = Ph + (ptrdiff_t)(drel - 17) * DK;
          f32x4 t2[3];
          t2[0] = exp4(band_gemm(pb2, 0, c, q, qw0, qw1));
          t2[1] = exp4(band_gemm(pb2, 1, c, q, qw0, qw1));
          t2[2] = exp4(band_gemm(pb2, 2, c, q, qw0, qw1));
          WRITE_BAND(E2, t2)
        }
        const float* e1r = &E1[w][c][q * 8];
        const float* e2r = &E2[w][c][q * 8];
        float4 aA = *(const float4*)e1r, aB = *(const float4*)(e1r + 4);
        float4 bA = *(const float4*)e2r, bB = *(const float4*)(e2r + 4);
        float f1[8] = {aA.x, aA.y, aA.z, aA.w, aB.x, aB.y, aB.z, aB.w};
        float f2[8] = {bA.x, bA.y, bA.z, bA.w, bB.x, bB.y, bB.z, bB.w};
        float es[8] = {__expf(S0[0]), __expf(S0[1]), __expf(S0[2]), __expf(S0[3]),
                       __expf(S1[0]), __expf(S1[1]), __expf(S1[2]), __expf(S1[3])};
        float pr[8];
#pragma unroll
        for (int jj = 0; jj < 8; ++jj) {
          const int dlt = drel + joff[jj] - c;
          const float f = (dlt <= 0) ? f1[jj] : ((dlt == 1) ? 1.0f : f2[jj]);
          pr[jj] = es[jj] * f;
        }
        PV_FROM(pr, jl)
      } else {                           // ---- phase C: region-2 only ----
        if (!hv2) {                      // switch band A-operand to Q rows +1
          qv0 = *(const s16x8*)(Qvb + (size_t)(c + 1) * DK + q * 8);
          qv1 = *(const s16x8*)(Qvb + (size_t)(c + 1) * DK + 32 + q * 8);
        }
        const ushortT* pb2 = Ph + (ptrdiff_t)(drel - 17) * DK;
        if (hv2) e[0] = e[2];
        else { e[0] = exp4(band_gemm(pb2, 0, c, q, qv0, qv1)); hv2 = true; }
        e[1] = exp4(band_gemm(pb2, 1, c, q, qv0, qv1));
        e[2] = exp4(band_gemm(pb2, 2, c, q, qv0, qv1));
        WRITE_BAND(E1, e)
        const float* e1r = &E1[w][c][q * 8];
        float4 fA = *(const float4*)e1r, fB = *(const float4*)(e1r + 4);
        float pr[8] = {__expf(S0[0]) * fA.x, __expf(S0[1]) * fA.y,
                       __expf(S0[2]) * fA.z, __expf(S0[3]) * fA.w,
                       __expf(S1[0]) * fB.x, __expf(S1[1]) * fB.y,
                       __expf(S1[2]) * fB.z, __expf(S1[3]) * fB.w};
        PV_FROM(pr, jl)
      }
    }
    __syncthreads();                     // all waves done reading Ks/Vs
    if (more) {
      *(uint4*)&Ks[tid >> 3][(tid & 7) * 8] = k0v;
      *(uint4*)&Ks[32 + (tid >> 3)][(tid & 7) * 8] = k1v;
      *(uint4*)&Vs[tid >> 2][(tid & 3) * 16] = v0v;
      *(uint4*)&Vs[tid >> 2][(tid & 3) * 16 + 8] = v1v;
    }
    __syncthreads();                     // staging visible
  }

  // ---- epilogue (rows exclusive to this wave) ----
  lrow += __shfl_xor(lrow, 16);
  lrow += __shfl_xor(lrow, 32);
  if (q == 0) Lb[w][c] = lrow;
  float inv[4];
#pragma unroll
  for (int r = 0; r < 4; ++r) inv[r] = 1.0f / Lb[w][q * 4 + r];
#pragma unroll
  for (int dt = 0; dt < 4; ++dt)
#pragma unroll
    for (int r = 0; r < 4; ++r) {
      const int i = iw + q * 4 + r;
      ctxb[((size_t)b * SEQ + i) * DM + h * DK + dt * 16 + c] = f2bf(O[dt][r] * inv[r]);
    }
}

extern "C" void kernel_launch(void* const* d_in, const int* in_sizes, int n_in,
                              void* d_out, int out_size, void* d_ws, size_t ws_size,
                              hipStream_t stream) {
  (void)in_sizes; (void)n_in; (void)out_size; (void)ws_size;
  const float* X   = (const float*)d_in[0];
  const float* PE  = (const float*)d_in[1];
  const float* Wq  = (const float*)d_in[2];
  const float* Wk  = (const float*)d_in[3];
  const float* Wv  = (const float*)d_in[4];
  const float* Wo  = (const float*)d_in[5];
  const float* Wp  = (const float*)d_in[6];
  const float* ubv = (const float*)d_in[7];
  const float* vbv = (const float*)d_in[8];

  const size_t NX = (size_t)4 * SEQ * DM;   // 4 Mi
  const size_t NP = (size_t)SEQ * DM;       // 1 Mi
  const size_t NW = (size_t)DM * DM;        // 256 Ki
  ushortT* Xb  = (ushortT*)d_ws;
  ushortT* PEb = Xb + NX;
  ushortT* Wt  = PEb + NP;                  // [Wq^T;Wk^T;Wv^T;Wp^T;Wo^T] bf16
  ushortT* qu  = Wt + 5 * NW;
  ushortT* qv  = qu + NX;
  ushortT* kb  = qv + NX;                   // qw overread from qv lands here: safe
  ushortT* vt  = kb + NX;
  ushortT* pp  = vt + NX;                   // NH*PPAD*DK
  ushortT* ctx = pp + (size_t)NH * PPAD * DK;
  float* outp = (float*)d_out;

  hipLaunchKernelGGL(cast_in, dim3((NX + NP) / 4 / 256), dim3(256), 0, stream, X, PE, Xb, PEb);
  hipLaunchKernelGGL(transpose_w, dim3(16, 16, 5), dim3(32, 8), 0, stream, Wq, Wk, Wv, Wp, Wo, Wt);
  dim3 blk(256);
  hipLaunchKernelGGL(gemm_mfma, dim3(64, 12), blk, 0, stream, Xb, Wt, ubv, vbv,
                     qu, qv, kb, vt, (float*)nullptr, 0);
  hipLaunchKernelGGL(gemm_mfma, dim3(16, 4), blk, 0, stream, PEb, Wt + 3 * NW, ubv, vbv,
                     pp, (ushortT*)nullptr, (ushortT*)nullptr, (ushortT*)nullptr, (float*)nullptr, 3);
  hipLaunchKernelGGL(attn_mfma, dim3(1024), blk, 0, stream, qu, qv, kb, vt, pp, ctx);
  hipLaunchKernelGGL(gemm_mfma, dim3(64, 4), blk, 0, stream, ctx, Wt + 4 * NW, ubv, vbv,
                     (ushortT*)nullptr, (ushortT*)nullptr, (ushortT*)nullptr, (ushortT*)nullptr, outp, 4);
}